// Round 9
// baseline (75.889 us; speedup 1.0000x reference)
//
#include <hip/hip_runtime.h>
#include <math.h>

#define N_STATES 64
#define DIM 16
#define N_CAT 2080
#define N_CAT_PAD 2304         // table stride; entries >= 2080 never touched
#define N_ROWS 4096            // BATCH * L = 256 * 16
#define ROWS_PER_BLOCK 4
#define GRID_ROWS (N_ROWS / ROWS_PER_BLOCK)   // 1024 blocks
#define N_SLOTS 64
#define BLOCKS_PER_SLOT (GRID_ROWS / N_SLOTS) // 16
#define N_FULL_ITER 8          // 8 * 256 = 2048 categories, uniform
#define N_TAIL 32              // cats 2048..2079 handled by tid < 32
#define TAB_N 1024             // ndtr lerp table: x in [-8,8], h = 1/64
#define SKIP_MARGIN 18.0f      // drop terms > 18 nats below running max
#define LOG2PI 1.8378770664093453f
#define SQRT1_2 0.70710678118654752f
#define LN2 0.69314718055994531f

// ws layout (float slots):
//   [0, 2304*4)            tab4: float4 {K, c0p, h, rs}
//   [2304*4, 2304*6)       tab2: float2 {ab(bitcast int), sqc}
//   meta = ws + 2304*6, spread on distinct 128B lines:
//     meta[0]              lse of log_pi
//     meta[32]             grand sum (float)
//     meta[64]             global ticket (int)
//     meta[96 + 32*i]      slot sum i, i<64
//     meta[96 + 32*64 + 32*i]  slot ticket i (int)
// c0p = log_pi + 0.5*(log2pi - log cl) - 0.5*|mu_b|^2 (diag: log_pi - 0.5*|mu_b|^2 + ln2)
// h = 0.5*recip; rs = recip*sqrt(cl); sqc = sqrt(cl)   (diag: h=rs=0, sqc=1e4 -> diff=0.5)
// eta2 = dot*rs, eta1 = eta2 + sqc, diff = ndtr(eta1) - ndtr(eta2)

#define META_GRAND  32
#define META_GTICK  64
#define META_SSUM(i)  (96 + 32 * (i))
#define META_STICK(i) (96 + 32 * N_SLOTS + 32 * (i))

// Numerical Recipes erfc approximation: 1 rcp + ~11 fma + 1 exp, rel err ~1e-7.
// Used only to BUILD the per-block ndtr table.
__device__ __forceinline__ float erfc_fast(float x) {
    const float ax = fabsf(x);
    const float t = __builtin_amdgcn_rcpf(fmaf(0.5f, ax, 1.0f));
    float p = 0.17087277f;
    p = fmaf(t, p, -0.82215223f);
    p = fmaf(t, p,  1.48851587f);
    p = fmaf(t, p, -1.13520398f);
    p = fmaf(t, p,  0.27886807f);
    p = fmaf(t, p, -0.18628806f);
    p = fmaf(t, p,  0.09678418f);
    p = fmaf(t, p,  0.37409196f);
    p = fmaf(t, p,  1.00002368f);
    p = fmaf(t, p, -1.26551223f);
    const float w = fmaf(-ax, ax, p);       // -x^2 + P(t)
    const float r = t * __expf(w);
    return (x < 0.0f) ? (2.0f - r) : r;
}

__device__ __forceinline__ float atom_addf(float* p, float v) {
    return __hip_atomic_fetch_add(p, v, __ATOMIC_RELAXED, __HIP_MEMORY_SCOPE_AGENT);
}
__device__ __forceinline__ int atom_addi(int* p, int v) {
    return __hip_atomic_fetch_add(p, v, __ATOMIC_RELAXED, __HIP_MEMORY_SCOPE_AGENT);
}

__global__ __launch_bounds__(256) void precompute_kernel(
        const float* __restrict__ mu,
        const float* __restrict__ log_pi,
        float* __restrict__ ws) {
    const int tid = threadIdx.x;
    float* meta = ws + N_CAT_PAD * 6;

    if (blockIdx.x == 9) {
        // lse of log_pi (softmax normalizer) + zero all reduction slots.
        __shared__ float red[256];
        float mx = -INFINITY;
        for (int c = tid; c < N_CAT; c += 256) mx = fmaxf(mx, log_pi[c]);
        red[tid] = mx; __syncthreads();
        for (int off = 128; off > 0; off >>= 1) {
            if (tid < off) red[tid] = fmaxf(red[tid], red[tid + off]);
            __syncthreads();
        }
        const float gmax = red[0]; __syncthreads();
        float sm = 0.f;
        for (int c = tid; c < N_CAT; c += 256) sm += __expf(log_pi[c] - gmax);
        red[tid] = sm; __syncthreads();
        for (int off = 128; off > 0; off >>= 1) {
            if (tid < off) red[tid] += red[tid + off];
            __syncthreads();
        }
        if (tid == 0) {
            meta[0] = gmax + logf(red[0]);       // lse
            meta[META_GRAND] = 0.f;
            *(int*)(meta + META_GTICK) = 0;
        }
        if (tid < N_SLOTS) {
            meta[META_SSUM(tid)] = 0.f;
            *(int*)(meta + META_STICK(tid)) = 0;
        }
        return;
    }

    const int c = blockIdx.x * 256 + tid;
    if (c >= N_CAT) return;

    // invert c -> (a,b), a<=b, row-major upper-triangular enumeration
    int a = (int)((129.0 - sqrt(129.0 * 129.0 - 8.0 * (double)c)) * 0.5);
    a = max(0, min(63, a));
    while (a > 0  && (64 * a - a * (a - 1) / 2) > c) a--;
    while (a < 63 && (64 * (a + 1) - (a + 1) * a / 2) <= c) a++;
    const int b = a + (c - (64 * a - a * (a - 1) / 2));

    float inv = 0.f, K = 0.f, m2b = 0.f;
    for (int d = 0; d < DIM; ++d) {
        const float ma = mu[d * N_STATES + a];
        const float mb = mu[d * N_STATES + b];
        const float al = mb - ma;           // alpha = mu_B - mu_A
        inv += al * al;
        K   += al * mb;
        m2b += mb * mb;
    }
    const float cl   = fminf(fmaxf(inv, 1e-12f), 1e30f);
    const float lp   = log_pi[c];           // softmax -lse applied at the end
    const bool  diag = (a == b);
    const float sqc  = diag ? 1e4f : sqrtf(cl);   // diag: eta1 clamps -> ndtr=1
    const float rcp  = diag ? 0.f : 1.f / inv;

    float c0p = lp - 0.5f * m2b;
    c0p += diag ? LN2 : 0.5f * (LOG2PI - logf(cl));

    float4* tab4 = (float4*)ws;
    float2* tab2 = (float2*)(ws + N_CAT_PAD * 4);
    tab4[c] = make_float4(K, c0p, 0.5f * rcp, rcp * sqc);
    float2 t2; t2.x = __int_as_float(a | (b << 16)); t2.y = sqc;
    tab2[c] = t2;
}

__global__ __launch_bounds__(256) void row_kernel(
        const float* __restrict__ z,
        const float* __restrict__ mu,
        float* __restrict__ ws,
        float* __restrict__ out) {
    const int blk = blockIdx.x;
    const int tid = threadIdx.x;
    __shared__ float2 ndtr_tab[TAB_N];      // {ndtr(x_j), ndtr(x_{j+1})-ndtr(x_j)}
    __shared__ float4 zdot4[N_STATES];      // {row0..row3} interleaved per state
    __shared__ float  zz_sh[ROWS_PER_BLOCK];
    __shared__ float  wred[ROWS_PER_BLOCK][4];

    const float* zr = z + (blk * ROWS_PER_BLOCK) * DIM;  // 64 consecutive floats
    {
        const int r = tid >> 6, st = tid & 63;           // wave r -> row r
        float acc = 0.f;
        #pragma unroll
        for (int d = 0; d < DIM; ++d) acc += zr[r * DIM + d] * mu[d * N_STATES + st];
        ((float*)zdot4)[st * 4 + r] = acc;
        if (tid < ROWS_PER_BLOCK) {
            float zq = 0.f;
            #pragma unroll
            for (int d = 0; d < DIM; ++d) zq += zr[tid * DIM + d] * zr[tid * DIM + d];
            zz_sh[tid] = zq;
        }
    }
    // build the ndtr lerp table: x = (j-512)/64
    for (int j = tid; j < TAB_N; j += 256) {
        const float x0 = (float)(j - 512) * (1.0f / 64.0f);
        const float v0 = 0.5f * erfc_fast(-x0 * SQRT1_2);
        const float v1 = 0.5f * erfc_fast(-(x0 + (1.0f / 64.0f)) * SQRT1_2);
        ndtr_tab[j] = make_float2(v0, v1 - v0);
    }
    __syncthreads();

    const float4* tab4 = (const float4*)ws;
    const float2* tab2 = (const float2*)(ws + N_CAT_PAD * 4);

    float s[ROWS_PER_BLOCK] = {0.f, 0.f, 0.f, 0.f};
    float kmax = -1e30f;                    // per-lane running max of k

    auto ndtr_l = [&](float e) -> float {
        float xi = fminf(fmaxf(fmaf(e, 64.f, 512.f), 0.f), 1023.9f);
        const float fl = floorf(xi);
        const float fr = xi - fl;
        const float2 t = ndtr_tab[(int)fl];
        return fmaf(fr, t.y, t.x);
    };

    auto body = [&](int c) {
        const float4 t4 = tab4[c];          // {K, c0p, h, rs}
        const float2 t2 = tab2[c];          // {ab, sqc}
        const int ab = __float_as_int(t2.x);
        const float4 da = zdot4[ab & 0xffff];
        const float4 db = zdot4[ab >> 16];
        float dotv[ROWS_PER_BLOCK], kv[ROWS_PER_BLOCK];
        #pragma unroll
        for (int r = 0; r < ROWS_PER_BLOCK; ++r) {
            const float sa = ((const float*)&da)[r];
            const float sb = ((const float*)&db)[r];
            const float dot = (sb - sa) - t4.x;
            dotv[r] = dot;
            kv[r] = fmaf(dot * t4.z, dot, t4.y + sb);
        }
        const float m4 = fmaxf(fmaxf(kv[0], kv[1]), fmaxf(kv[2], kv[3]));
        // Skip gate: terms > SKIP_MARGIN nats below the lane's running max
        // contribute < e^-18 relative -> drop without touching LDS/exp.
        if (m4 > kmax - SKIP_MARGIN) {
            #pragma unroll
            for (int r = 0; r < ROWS_PER_BLOCK; ++r) {
                const float e2 = dotv[r] * t4.w;        // eta2
                const float e1 = e2 + t2.y;             // eta1 = eta2 + sqc
                const float diff = fmaxf(ndtr_l(e1) - ndtr_l(e2), 0.f);
                s[r] = fmaf(diff, __expf(kv[r]), s[r]);
            }
        }
        kmax = fmaxf(kmax, m4);
    };

    #pragma unroll
    for (int i = 0; i < N_FULL_ITER; ++i) body(tid + i * 256);
    if (tid < N_TAIL) body(2048 + tid);     // cats 2048..2079; waves 1-3 skip

    #pragma unroll
    for (int off = 32; off > 0; off >>= 1) {
        #pragma unroll
        for (int r = 0; r < ROWS_PER_BLOCK; ++r) s[r] += __shfl_xor(s[r], off);
    }
    const int wave = tid >> 6;
    if ((tid & 63) == 0) {
        #pragma unroll
        for (int r = 0; r < ROWS_PER_BLOCK; ++r) wred[r][wave] = s[r];
    }
    __syncthreads();

    if (tid == 0) {
        float* meta = ws + N_CAT_PAD * 6;
        float contrib = 0.f;
        #pragma unroll
        for (int r = 0; r < ROWS_PER_BLOCK; ++r) {
            const float S = (wred[r][0] + wred[r][1]) + (wred[r][2] + wred[r][3]);
            contrib += logf(S) - 0.5f * zz_sh[r];
        }
        // Hierarchical relaxed-atomic reduction, all ordering via data deps.
        const int slot = blk & (N_SLOTS - 1);
        const float old = atom_addf(meta + META_SSUM(slot), contrib);
        int inc = 1;
        asm volatile("" : "+v"(inc) : "v"(old));          // ticket after add done
        const int t = atom_addi((int*)(meta + META_STICK(slot)), inc);
        if (t == BLOCKS_PER_SLOT - 1) {
            // slot winner: all 16 slot adds complete -> forward slot total
            const float ssum = atom_addf(meta + META_SSUM(slot), 0.f);
            const float old2 = atom_addf(meta + META_GRAND, ssum);
            int inc2 = 1;
            asm volatile("" : "+v"(inc2) : "v"(old2));
            const int g = atom_addi((int*)(meta + META_GTICK), inc2);
            if (g == N_SLOTS - 1) {
                const float total = atom_addf(meta + META_GRAND, 0.f);
                out[0] = total * (1.0f / N_ROWS) - meta[0] - 8.0f * LOG2PI;
            }
        }
    }
}

extern "C" void kernel_launch(void* const* d_in, const int* in_sizes, int n_in,
                              void* d_out, int out_size, void* d_ws, size_t ws_size,
                              hipStream_t stream) {
    const float* z      = (const float*)d_in[0];
    const float* mu     = (const float*)d_in[1];
    const float* log_pi = (const float*)d_in[2];
    float* ws = (float*)d_ws;

    precompute_kernel<<<10, 256, 0, stream>>>(mu, log_pi, ws);
    row_kernel<<<GRID_ROWS, 256, 0, stream>>>(z, mu, ws, (float*)d_out);
}

// Round 10
// 72.125 us; speedup vs baseline: 1.0522x; 1.0522x over previous
//
#include <hip/hip_runtime.h>
#include <math.h>

#define N_STATES 64
#define DIM 16
#define N_CAT 2080
#define N_CAT_PAD 2304         // table stride; entries >= 2080 never touched
#define N_ROWS 4096            // BATCH * L = 256 * 16
#define ROWS_PER_BLOCK 2
#define GRID_ROWS (N_ROWS / ROWS_PER_BLOCK)   // 2048 blocks -> 8 blocks/CU, 100% occ
#define N_SLOTS 64
#define BLOCKS_PER_SLOT (GRID_ROWS / N_SLOTS) // 32
#define N_FULL_ITER 8          // 8 * 256 = 2048 categories, uniform
#define N_TAIL 32              // cats 2048..2079 handled by tid < 32
#define TAB_N 1024             // ndtr lerp table: x in [-8,8], h = 1/64
#define LOG2PI 1.8378770664093453f
#define SQRT1_2 0.70710678118654752f
#define LN2 0.69314718055994531f

// ws layout (float slots):
//   [0, 2304*4)            tab4: float4 {K, c0p, h, rs}
//   [2304*4, 2304*6)       tab2: float2 {ab(bitcast int), sqc}
//   meta = ws + 2304*6, spread on distinct 128B lines:
//     meta[0]              lse of log_pi
//     meta[32]             grand sum (float)
//     meta[64]             global ticket (int)
//     meta[96 + 32*i]      slot sum i, i<64
//     meta[96 + 32*64 + 32*i]  slot ticket i (int)
// c0p = log_pi + 0.5*(log2pi - log cl) - 0.5*|mu_b|^2 (diag: log_pi - 0.5*|mu_b|^2 + ln2)
// h = 0.5*recip; rs = recip*sqrt(cl); sqc = sqrt(cl)   (diag: h=rs=0, sqc=1e4 -> diff=0.5)
// eta2 = dot*rs, eta1 = eta2 + sqc, diff = ndtr(eta1) - ndtr(eta2)

#define META_GRAND  32
#define META_GTICK  64
#define META_SSUM(i)  (96 + 32 * (i))
#define META_STICK(i) (96 + 32 * N_SLOTS + 32 * (i))

// Numerical Recipes erfc approximation: 1 rcp + ~11 fma + 1 exp, rel err ~1e-7.
// Used only to BUILD the per-block ndtr table.
__device__ __forceinline__ float erfc_fast(float x) {
    const float ax = fabsf(x);
    const float t = __builtin_amdgcn_rcpf(fmaf(0.5f, ax, 1.0f));
    float p = 0.17087277f;
    p = fmaf(t, p, -0.82215223f);
    p = fmaf(t, p,  1.48851587f);
    p = fmaf(t, p, -1.13520398f);
    p = fmaf(t, p,  0.27886807f);
    p = fmaf(t, p, -0.18628806f);
    p = fmaf(t, p,  0.09678418f);
    p = fmaf(t, p,  0.37409196f);
    p = fmaf(t, p,  1.00002368f);
    p = fmaf(t, p, -1.26551223f);
    const float w = fmaf(-ax, ax, p);       // -x^2 + P(t)
    const float r = t * __expf(w);
    return (x < 0.0f) ? (2.0f - r) : r;
}

__device__ __forceinline__ float atom_addf(float* p, float v) {
    return __hip_atomic_fetch_add(p, v, __ATOMIC_RELAXED, __HIP_MEMORY_SCOPE_AGENT);
}
__device__ __forceinline__ int atom_addi(int* p, int v) {
    return __hip_atomic_fetch_add(p, v, __ATOMIC_RELAXED, __HIP_MEMORY_SCOPE_AGENT);
}

__global__ __launch_bounds__(256) void precompute_kernel(
        const float* __restrict__ mu,
        const float* __restrict__ log_pi,
        float* __restrict__ ws) {
    const int tid = threadIdx.x;
    float* meta = ws + N_CAT_PAD * 6;

    if (blockIdx.x == 9) {
        // lse of log_pi (softmax normalizer) + zero all reduction slots.
        __shared__ float red[256];
        float mx = -INFINITY;
        for (int c = tid; c < N_CAT; c += 256) mx = fmaxf(mx, log_pi[c]);
        red[tid] = mx; __syncthreads();
        for (int off = 128; off > 0; off >>= 1) {
            if (tid < off) red[tid] = fmaxf(red[tid], red[tid + off]);
            __syncthreads();
        }
        const float gmax = red[0]; __syncthreads();
        float sm = 0.f;
        for (int c = tid; c < N_CAT; c += 256) sm += __expf(log_pi[c] - gmax);
        red[tid] = sm; __syncthreads();
        for (int off = 128; off > 0; off >>= 1) {
            if (tid < off) red[tid] += red[tid + off];
            __syncthreads();
        }
        if (tid == 0) {
            meta[0] = gmax + logf(red[0]);       // lse
            meta[META_GRAND] = 0.f;
            *(int*)(meta + META_GTICK) = 0;
        }
        if (tid < N_SLOTS) {
            meta[META_SSUM(tid)] = 0.f;
            *(int*)(meta + META_STICK(tid)) = 0;
        }
        return;
    }

    const int c = blockIdx.x * 256 + tid;
    if (c >= N_CAT) return;

    // invert c -> (a,b), a<=b, row-major upper-triangular enumeration
    int a = (int)((129.0 - sqrt(129.0 * 129.0 - 8.0 * (double)c)) * 0.5);
    a = max(0, min(63, a));
    while (a > 0  && (64 * a - a * (a - 1) / 2) > c) a--;
    while (a < 63 && (64 * (a + 1) - (a + 1) * a / 2) <= c) a++;
    const int b = a + (c - (64 * a - a * (a - 1) / 2));

    float inv = 0.f, K = 0.f, m2b = 0.f;
    for (int d = 0; d < DIM; ++d) {
        const float ma = mu[d * N_STATES + a];
        const float mb = mu[d * N_STATES + b];
        const float al = mb - ma;           // alpha = mu_B - mu_A
        inv += al * al;
        K   += al * mb;
        m2b += mb * mb;
    }
    const float cl   = fminf(fmaxf(inv, 1e-12f), 1e30f);
    const float lp   = log_pi[c];           // softmax -lse applied at the end
    const bool  diag = (a == b);
    const float sqc  = diag ? 1e4f : sqrtf(cl);   // diag: eta1 clamps -> ndtr=1
    const float rcp  = diag ? 0.f : 1.f / inv;

    float c0p = lp - 0.5f * m2b;
    c0p += diag ? LN2 : 0.5f * (LOG2PI - logf(cl));

    float4* tab4 = (float4*)ws;
    float2* tab2 = (float2*)(ws + N_CAT_PAD * 4);
    tab4[c] = make_float4(K, c0p, 0.5f * rcp, rcp * sqc);
    float2 t2; t2.x = __int_as_float(a | (b << 16)); t2.y = sqc;
    tab2[c] = t2;
}

__global__ __launch_bounds__(256) void row_kernel(
        const float* __restrict__ z,
        const float* __restrict__ mu,
        float* __restrict__ ws,
        float* __restrict__ out) {
    const int blk = blockIdx.x;
    const int tid = threadIdx.x;
    __shared__ float2 ndtr_tab[TAB_N];      // {ndtr(x_j), ndtr(x_{j+1})-ndtr(x_j)}
    __shared__ float2 zdot2[N_STATES];      // {row0, row1} per state
    __shared__ float  zz_sh[ROWS_PER_BLOCK];
    __shared__ float  wred[ROWS_PER_BLOCK][4];

    const float* zr = z + (blk * ROWS_PER_BLOCK) * DIM;  // 32 consecutive floats
    if (tid < 128) {
        const int r = tid >> 6, st = tid & 63;           // wave r -> row r
        float acc = 0.f;
        #pragma unroll
        for (int d = 0; d < DIM; ++d) acc += zr[r * DIM + d] * mu[d * N_STATES + st];
        ((float*)zdot2)[st * 2 + r] = acc;
        if (tid < ROWS_PER_BLOCK) {
            float zq = 0.f;
            #pragma unroll
            for (int d = 0; d < DIM; ++d) zq += zr[tid * DIM + d] * zr[tid * DIM + d];
            zz_sh[tid] = zq;
        }
    }
    // build the ndtr lerp table: x = (j-512)/64
    for (int j = tid; j < TAB_N; j += 256) {
        const float x0 = (float)(j - 512) * (1.0f / 64.0f);
        const float v0 = 0.5f * erfc_fast(-x0 * SQRT1_2);
        const float v1 = 0.5f * erfc_fast(-(x0 + (1.0f / 64.0f)) * SQRT1_2);
        ndtr_tab[j] = make_float2(v0, v1 - v0);
    }
    __syncthreads();

    const float4* tab4 = (const float4*)ws;
    const float2* tab2 = (const float2*)(ws + N_CAT_PAD * 4);

    float s0 = 0.f, s1 = 0.f;

    auto ndtr_l = [&](float e) -> float {
        float xi = fminf(fmaxf(fmaf(e, 64.f, 512.f), 0.f), 1023.9f);
        const float fl = floorf(xi);
        const float fr = xi - fl;
        const float2 t = ndtr_tab[(int)fl];
        return fmaf(fr, t.y, t.x);
    };

    auto body = [&](int c) {
        const float4 t4 = tab4[c];          // {K, c0p, h, rs}
        const float2 t2 = tab2[c];          // {ab, sqc}
        const int ab = __float_as_int(t2.x);
        const float2 da = zdot2[ab & 0xffff];
        const float2 db = zdot2[ab >> 16];
        {   // row 0
            const float dot = (db.x - da.x) - t4.x;
            const float e2 = dot * t4.w;
            const float e1 = e2 + t2.y;
            const float k  = fmaf(dot * t4.z, dot, t4.y + db.x);
            const float diff = fmaxf(ndtr_l(e1) - ndtr_l(e2), 0.f);
            s0 = fmaf(diff, __expf(k), s0);
        }
        {   // row 1
            const float dot = (db.y - da.y) - t4.x;
            const float e2 = dot * t4.w;
            const float e1 = e2 + t2.y;
            const float k  = fmaf(dot * t4.z, dot, t4.y + db.y);
            const float diff = fmaxf(ndtr_l(e1) - ndtr_l(e2), 0.f);
            s1 = fmaf(diff, __expf(k), s1);
        }
    };

    #pragma unroll
    for (int i = 0; i < N_FULL_ITER; ++i) body(tid + i * 256);
    if (tid < N_TAIL) body(2048 + tid);     // cats 2048..2079; waves 1-3 skip

    #pragma unroll
    for (int off = 32; off > 0; off >>= 1) {
        s0 += __shfl_xor(s0, off);
        s1 += __shfl_xor(s1, off);
    }
    const int wave = tid >> 6;
    if ((tid & 63) == 0) { wred[0][wave] = s0; wred[1][wave] = s1; }
    __syncthreads();

    if (tid == 0) {
        float* meta = ws + N_CAT_PAD * 6;
        const float S0 = (wred[0][0] + wred[0][1]) + (wred[0][2] + wred[0][3]);
        const float S1 = (wred[1][0] + wred[1][1]) + (wred[1][2] + wred[1][3]);
        const float contrib = logf(S0) + logf(S1)
                            - 0.5f * (zz_sh[0] + zz_sh[1]);
        // Hierarchical relaxed-atomic reduction, all ordering via data deps.
        const int slot = blk & (N_SLOTS - 1);
        const float old = atom_addf(meta + META_SSUM(slot), contrib);
        int inc = 1;
        asm volatile("" : "+v"(inc) : "v"(old));          // ticket after add done
        const int t = atom_addi((int*)(meta + META_STICK(slot)), inc);
        if (t == BLOCKS_PER_SLOT - 1) {
            // slot winner: all slot adds complete -> forward slot total
            const float ssum = atom_addf(meta + META_SSUM(slot), 0.f);
            const float old2 = atom_addf(meta + META_GRAND, ssum);
            int inc2 = 1;
            asm volatile("" : "+v"(inc2) : "v"(old2));
            const int g = atom_addi((int*)(meta + META_GTICK), inc2);
            if (g == N_SLOTS - 1) {
                const float total = atom_addf(meta + META_GRAND, 0.f);
                out[0] = total * (1.0f / N_ROWS) - meta[0] - 8.0f * LOG2PI;
            }
        }
    }
}

extern "C" void kernel_launch(void* const* d_in, const int* in_sizes, int n_in,
                              void* d_out, int out_size, void* d_ws, size_t ws_size,
                              hipStream_t stream) {
    const float* z      = (const float*)d_in[0];
    const float* mu     = (const float*)d_in[1];
    const float* log_pi = (const float*)d_in[2];
    float* ws = (float*)d_ws;

    precompute_kernel<<<10, 256, 0, stream>>>(mu, log_pi, ws);
    row_kernel<<<GRID_ROWS, 256, 0, stream>>>(z, mu, ws, (float*)d_out);
}